// Round 4
// baseline (312.938 us; speedup 1.0000x reference)
//
#include <hip/hip_runtime.h>
#include <stdint.h>

// y[b,s,m] = sum_n x[b,s,n] * W[m,n] + bias[m], W from TT cores (bf16, built once).
// Pipeline: build_w (8 MB bf16) -> fused 8-phase 256^2 GEMM.
// A = fp32 X converted to bf16 in-kernel with a DOUBLE-BUFFERED register stage
// (loads for tile t+2 issued at iter t; cvt+ds_write of tile t+1 at iter t ->
// ~6 phases of latency cover).  B = bf16 W via global_load_lds.

typedef __attribute__((ext_vector_type(8))) __bf16 bf16x8;
typedef __attribute__((ext_vector_type(4))) float f32x4;
typedef __attribute__((ext_vector_type(8))) unsigned short us8;

#define M_TOT 16384
#define N_TOT 2048
#define K_TOT 2048

__device__ __forceinline__ unsigned short f2bf(float f) {
  union { float f; unsigned u; } v; v.f = f;
  unsigned u = v.u;
  u += 0x7FFFu + ((u >> 16) & 1u);   // RNE
  return (unsigned short)(u >> 16);
}

__device__ __forceinline__ void gld_lds16(const void* g, void* l) {
  __builtin_amdgcn_global_load_lds(
      (const __attribute__((address_space(1))) unsigned int*)g,
      (__attribute__((address_space(3))) unsigned int*)l, 16, 0, 0);
}

#define BARRIER() __builtin_amdgcn_s_barrier()
#define WAIT_LGKM0() asm volatile("s_waitcnt lgkmcnt(0)" ::: "memory")
#define WAIT_VM(N) asm volatile("s_waitcnt vmcnt(" #N ")" ::: "memory")

// ---------------------------------------------------------------------------
// Kernel 1: reconstruct W (bf16). W[n,k], n=out (2048), k=in (2048).
// ---------------------------------------------------------------------------
__global__ void build_w_kernel(const float* __restrict__ c1,
                               const float* __restrict__ c2,
                               unsigned short* __restrict__ W) {
  int idx = blockIdx.x * 256 + threadIdx.x;      // n*2048 + k
  int k = idx & (K_TOT - 1);
  int n = idx >> 11;
  int i = n >> 9, ob = n & 511;
  int m1 = ob >> 4, m2 = ob & 15;
  int j = k >> 9, ib = k & 511;
  int n1 = ib >> 4, n2 = ib & 15;
  const float* a = c1 + ((((i * 4 + j) * 32 + m1) * 32 + n1) * 16);
  const float* b = c2 + ((i * 4 + j) * 4096 + m2 * 16 + n2);
  float s = 0.f;
#pragma unroll
  for (int r = 0; r < 16; ++r) s += a[r] * b[r * 256];
  W[idx] = f2bf(s);
}

// ---------------------------------------------------------------------------
// Kernel 2: fused 8-phase 256x256 GEMM, BK=64, 512 thr (8 waves 2Mx4N).
// LDS 128 KiB: [buf2][sect4][128x64 bf16]; sect 0/1 = A halves, 2/3 = B halves.
// XOR swizzle blk^=(row&7) on both write and read sides.
// ---------------------------------------------------------------------------
__global__ __launch_bounds__(512, 2) void gemm_fused_kernel(
    const float* __restrict__ X, const unsigned short* __restrict__ W,
    const float* __restrict__ bias, float* __restrict__ Y) {
  __shared__ __align__(16) unsigned short lds[2][4][128 * 64];

  const int tid = threadIdx.x;
  const int lane = tid & 63;
  const int wid = tid >> 6;
  const int wm = wid >> 2, wn = wid & 3;     // 2 x 4 wave grid

  // bijective XCD swizzle: 512 wgs, 8 XCDs, 64-wg chunks; 8 consecutive wgs
  // of a chunk share an mblk (A panel stays hot in the XCD's L2).
  const int bid = blockIdx.x;
  const int xcd = bid & 7, loc = bid >> 3;
  const int mblk = xcd * 8 + (loc >> 3);     // 0..63
  const int nblk = loc & 7;                  // 0..7
  const int m0 = mblk * 256, n0 = nblk * 256;

  // fragment read addressing
  const int fr = lane & 15, g = lane >> 4;
  const int swz = fr & 7;
  const int blkB0 = ((0 + g) ^ swz) * 16;    // ksub=0 byte offset of 16B block
  const int blkB1 = ((4 + g) ^ swz) * 16;    // ksub=1
  const int arow = fr * 128;                 // + m*2048 bytes
  const int brow = ((wn & 1) * 64 + fr) * 128;  // + n*2048 bytes

  // staging thread mapping: row-within-64 = tid>>3, 8-col block = tid&7
  const int sr = tid >> 3;
  const int b8 = tid & 7;
  const int scB = (b8 ^ (sr & 7)) * 8;       // B: inverse-swizzled global col
  const int ldsAoff = (b8 ^ (sr & 7)) * 8;   // A: swizzled LDS col (shorts)

  auto stageB = [&](int half, int buf, int kt) {
    const unsigned short* base = W + (size_t)(n0 + half * 128) * K_TOT + kt * 64 + scB;
#pragma unroll
    for (int i = 0; i < 2; ++i)
      gld_lds16(base + (size_t)(i * 64 + sr) * K_TOT,
                &lds[buf][2 + half][i * 4096 + wid * 512]);
  };

  auto loadA = [&](f32x4 (&ap)[2][4], int half, int kt) {
    const float* base = X + (size_t)(m0 + half * 128 + sr) * K_TOT + kt * 64 + b8 * 8;
#pragma unroll
    for (int i = 0; i < 2; ++i) {
      ap[half][i * 2 + 0] = *(const f32x4*)(base + (size_t)i * 64 * K_TOT);
      ap[half][i * 2 + 1] = *(const f32x4*)(base + (size_t)i * 64 * K_TOT + 4);
    }
  };
  auto writeA = [&](f32x4 (&ap)[2][4], int half, int buf) {
#pragma unroll
    for (int i = 0; i < 2; ++i) {
      us8 h;
#pragma unroll
      for (int v = 0; v < 4; ++v) {
        h[v]     = f2bf(ap[half][i * 2 + 0][v]);
        h[4 + v] = f2bf(ap[half][i * 2 + 1][v]);
      }
      *(us8*)&lds[buf][half][(i * 64 + sr) * 64 + ldsAoff] = h;
    }
  };

  auto ldA = [&](int c, int m, int ks) -> bf16x8 {
    const char* p = (const char*)&lds[c][wm][0] + arow + m * 2048 + (ks ? blkB1 : blkB0);
    return *(const bf16x8*)p;
  };
  auto ldB = [&](int c, int n, int ks) -> bf16x8 {
    const char* p = (const char*)&lds[c][2 + (wn >> 1)][0] + brow + n * 2048 + (ks ? blkB1 : blkB0);
    return *(const bf16x8*)p;
  };

  f32x4 acc[8][4];
#pragma unroll
  for (int m = 0; m < 8; ++m)
#pragma unroll
    for (int n = 0; n < 4; ++n) acc[m][n] = {0.f, 0.f, 0.f, 0.f};

  const int NT = K_TOT / 64;  // 32 K-tiles (even)

  f32x4 ap0[2][4], ap1[2][4];  // ping/pong A register stages (static indexing)
  bf16x8 bq[4][2];

  // --- prologue ---
  loadA(ap0, 0, 0); loadA(ap0, 1, 0);     // A(0): 8 loads
  stageB(0, 0, 0); stageB(1, 0, 0);       // B(0) -> buf0: 4
  stageB(0, 1, 1); stageB(1, 1, 1);       // B(1) -> buf1: 4
  loadA(ap1, 0, 1); loadA(ap1, 1, 1);     // A(1): 8 loads
  writeA(ap0, 0, 0); writeA(ap0, 1, 0);   // compiler inserts vmcnt for ap0 regs
  WAIT_VM(8);                             // B(0),B(1) landed (A(1) may be in flight)
  WAIT_LGKM0();                           // our A ds_writes drained
  BARRIER();

  // Steady-state iter t (c = t&1): q0/q1 issue A-loads for tile t+2 into apL;
  // q2/q3 stage B(t+2) via gld_lds + cvt/write A(t+1) from apW.
  // vmcnt derivation (issue order per iter: A(t+2)x8 @q0/q1, B(t+2)x2 @q2, x2 @q3):
  //   q2 wait 18 -> A0(t+1) complete (18 loads issued after it)
  //   q3 wait 12 -> A1(t+1) AND B(t+1) complete before next tile's q0 ds_reads
  auto body = [&](int t, int c, f32x4 (&apL)[2][4], f32x4 (&apW)[2][4]) {
#pragma unroll
    for (int q = 0; q < 4; ++q) {
      bf16x8 a0  = ldA(c, 2 * q, 0);
      bf16x8 a0k = ldA(c, 2 * q, 1);
      bf16x8 a1  = ldA(c, 2 * q + 1, 0);
      bf16x8 a1k = ldA(c, 2 * q + 1, 1);
      if (q == 0) {
#pragma unroll
        for (int n = 0; n < 4; ++n) {
          bq[n][0] = ldB(c, n, 0);
          bq[n][1] = ldB(c, n, 1);
        }
      }
      if (q == 0 && t + 2 < NT) loadA(apL, 0, t + 2);
      if (q == 1 && t + 2 < NT) loadA(apL, 1, t + 2);
      if (q == 2) {
        if (t + 2 < NT) { stageB(0, c, t + 2); WAIT_VM(18); }
        else if (t + 1 < NT) { WAIT_VM(4); }
        if (t + 1 < NT) writeA(apW, 0, c ^ 1);
      }
      if (q == 3) {
        if (t + 2 < NT) { stageB(1, c, t + 2); WAIT_VM(12); }
        else           { WAIT_VM(0); }       // tail drain
        if (t + 1 < NT) writeA(apW, 1, c ^ 1);
      }
      BARRIER();
      WAIT_LGKM0();
      __builtin_amdgcn_s_setprio(1);
#pragma unroll
      for (int n = 0; n < 4; ++n) {
        acc[2 * q][n]     = __builtin_amdgcn_mfma_f32_16x16x32_bf16(a0,  bq[n][0], acc[2 * q][n],     0, 0, 0);
        acc[2 * q][n]     = __builtin_amdgcn_mfma_f32_16x16x32_bf16(a0k, bq[n][1], acc[2 * q][n],     0, 0, 0);
        acc[2 * q + 1][n] = __builtin_amdgcn_mfma_f32_16x16x32_bf16(a1,  bq[n][0], acc[2 * q + 1][n], 0, 0, 0);
        acc[2 * q + 1][n] = __builtin_amdgcn_mfma_f32_16x16x32_bf16(a1k, bq[n][1], acc[2 * q + 1][n], 0, 0, 0);
      }
      __builtin_amdgcn_s_setprio(0);
      BARRIER();
    }
  };

  for (int tt = 0; tt < NT; tt += 2) {
    body(tt,     0, ap0, ap1);   // loads tile tt+2 -> ap0, writes tile tt+1 from ap1
    body(tt + 1, 1, ap1, ap0);   // loads tile tt+3 -> ap1, writes tile tt+2 from ap0
  }

  // epilogue: D layout col=lane&15, row=(lane>>4)*4+j  [verified]
  const int rb4 = g * 4;
#pragma unroll
  for (int n = 0; n < 4; ++n) {
    const int gc = n0 + wn * 64 + n * 16 + fr;
    const float bv = bias[gc];
#pragma unroll
    for (int m = 0; m < 8; ++m) {
#pragma unroll
      for (int j = 0; j < 4; ++j) {
        const int gr = m0 + wm * 128 + m * 16 + rb4 + j;
        Y[(size_t)gr * N_TOT + gc] = acc[m][n][j] + bv;
      }
    }
  }
}

extern "C" void kernel_launch(void* const* d_in, const int* in_sizes, int n_in,
                              void* d_out, int out_size, void* d_ws, size_t ws_size,
                              hipStream_t stream) {
  const float* x    = (const float*)d_in[0];
  const float* c1   = (const float*)d_in[1];
  const float* c2   = (const float*)d_in[2];
  const float* bias = (const float*)d_in[3];
  float* y          = (float*)d_out;
  unsigned short* W = (unsigned short*)d_ws;   // 2048*2048 bf16 = 8 MB

  build_w_kernel<<<(N_TOT * K_TOT) / 256, 256, 0, stream>>>(c1, c2, W);
  gemm_fused_kernel<<<(M_TOT / 256) * (N_TOT / 256), 512, 0, stream>>>(x, W, bias, y);
}

// Round 5
// 180.933 us; speedup vs baseline: 1.7296x; 1.7296x over previous
//
#include <hip/hip_runtime.h>
#include <stdint.h>

// y[b,s,m] = sum_n x[b,s,n] * W[m,n] + bias[m], W from TT cores (bf16, built once).
// Pipeline: prep (build_w + convert_x fused, one dispatch) -> 8-phase 256^2 GEMM.
// GEMM: A = bf16 X (pre-converted), B = bf16 W, both via global_load_lds;
// MFMA called with swapped operands so the epilogue stores f32x4 (coalesced).

typedef __attribute__((ext_vector_type(8))) __bf16 bf16x8;
typedef __attribute__((ext_vector_type(4))) float f32x4;
typedef __attribute__((ext_vector_type(4))) unsigned short us4;
typedef __attribute__((ext_vector_type(8))) unsigned short us8;

#define M_TOT 16384
#define N_TOT 2048
#define K_TOT 2048

__device__ __forceinline__ unsigned short f2bf(float f) {
  union { float f; unsigned u; } v; v.f = f;
  unsigned u = v.u;
  u += 0x7FFFu + ((u >> 16) & 1u);   // RNE
  return (unsigned short)(u >> 16);
}

__device__ __forceinline__ void gld_lds16(const void* g, void* l) {
  __builtin_amdgcn_global_load_lds(
      (const __attribute__((address_space(1))) unsigned int*)g,
      (__attribute__((address_space(3))) unsigned int*)l, 16, 0, 0);
}

#define BARRIER() __builtin_amdgcn_s_barrier()
#define WAIT_LGKM0() asm volatile("s_waitcnt lgkmcnt(0)" ::: "memory")
#define WAIT_VM0() asm volatile("s_waitcnt vmcnt(0)" ::: "memory")
#define WAIT_VM4() asm volatile("s_waitcnt vmcnt(4)" ::: "memory")

// ---------------------------------------------------------------------------
// Kernel 1: fused prep. With nconv>0: blocks [0,nconv) convert X fp32->bf16
// (1 us8/thread); blocks [nconv, nconv+16384) build W from TT cores.
// ---------------------------------------------------------------------------
__global__ void prep_kernel(const float* __restrict__ X,
                            unsigned short* __restrict__ Xb,
                            const float* __restrict__ c1,
                            const float* __restrict__ c2,
                            unsigned short* __restrict__ W,
                            int nconv) {
  const int bid = blockIdx.x;
  if (bid < nconv) {
    const size_t i = (size_t)bid * 256 + threadIdx.x;   // us8 index
    f32x4 a = ((const f32x4*)X)[i * 2];
    f32x4 b = ((const f32x4*)X)[i * 2 + 1];
    us8 h;
    h[0] = f2bf(a[0]); h[1] = f2bf(a[1]); h[2] = f2bf(a[2]); h[3] = f2bf(a[3]);
    h[4] = f2bf(b[0]); h[5] = f2bf(b[1]); h[6] = f2bf(b[2]); h[7] = f2bf(b[3]);
    ((us8*)Xb)[i] = h;
  } else {
    int idx = (bid - nconv) * 256 + threadIdx.x;   // n*2048 + k
    int k = idx & (K_TOT - 1);
    int n = idx >> 11;
    int i = n >> 9, ob = n & 511;
    int m1 = ob >> 4, m2 = ob & 15;
    int j = k >> 9, ib = k & 511;
    int n1 = ib >> 4, n2 = ib & 15;
    const float* a = c1 + ((((i * 4 + j) * 32 + m1) * 32 + n1) * 16);
    const float* b = c2 + ((i * 4 + j) * 4096 + m2 * 16 + n2);
    float s = 0.f;
#pragma unroll
    for (int r = 0; r < 16; ++r) s += a[r] * b[r * 256];
    W[idx] = f2bf(s);
  }
}

// ---------------------------------------------------------------------------
// Kernel 2: 8-phase 256x256 bf16 GEMM, BK=64, 512 thr (8 waves 2Mx4N).
// LDS 128 KiB: [buf2][sect4][128x64 bf16]; sect 0/1 = A halves, 2/3 = B halves.
// XOR swizzle both-sides (inverse-swizzled global source + swizzled ds_read).
// vmcnt counted (4), never 0 in steady state. MFMA operands swapped (W-frag
// first) so D is transposed: reg j walks N -> f32x4 coalesced epilogue.
// ---------------------------------------------------------------------------
__global__ __launch_bounds__(512, 2) void gemm8p_kernel(
    const unsigned short* __restrict__ Xb, const unsigned short* __restrict__ W,
    const float* __restrict__ bias, float* __restrict__ Y) {
  __shared__ __align__(16) unsigned short lds[2][4][128 * 64];

  const int tid = threadIdx.x;
  const int lane = tid & 63;
  const int wid = tid >> 6;
  const int wm = wid >> 2, wn = wid & 3;     // 2 x 4 wave grid

  const int bid = blockIdx.x;
  const int xcd = bid & 7, loc = bid >> 3;
  const int mblk = xcd * 8 + (loc >> 3);     // 0..63
  const int nblk = loc & 7;                  // 0..7
  const int m0 = mblk * 256, n0 = nblk * 256;

  const int fr = lane & 15, g = lane >> 4;
  const int swz = fr & 7;
  const int blkB0 = ((0 + g) ^ swz) * 16;
  const int blkB1 = ((4 + g) ^ swz) * 16;
  const int arow = fr * 128;
  const int brow = ((wn & 1) * 64 + fr) * 128;

  const int sr = tid >> 3;
  const int sc = ((tid & 7) ^ (sr & 7)) * 8;

  auto stageA = [&](int half, int buf, int kt) {
    const unsigned short* base = Xb + (size_t)(m0 + half * 128) * K_TOT + kt * 64 + sc;
#pragma unroll
    for (int i = 0; i < 2; ++i)
      gld_lds16(base + (size_t)(i * 64 + sr) * K_TOT,
                &lds[buf][half][i * 4096 + wid * 512]);
  };
  auto stageB = [&](int half, int buf, int kt) {
    const unsigned short* base = W + (size_t)(n0 + half * 128) * K_TOT + kt * 64 + sc;
#pragma unroll
    for (int i = 0; i < 2; ++i)
      gld_lds16(base + (size_t)(i * 64 + sr) * K_TOT,
                &lds[buf][2 + half][i * 4096 + wid * 512]);
  };
  auto ldA = [&](int c, int m, int ks) -> bf16x8 {
    const char* p = (const char*)&lds[c][wm][0] + arow + m * 2048 + (ks ? blkB1 : blkB0);
    return *(const bf16x8*)p;
  };
  auto ldB = [&](int c, int n, int ks) -> bf16x8 {
    const char* p = (const char*)&lds[c][2 + (wn >> 1)][0] + brow + n * 2048 + (ks ? blkB1 : blkB0);
    return *(const bf16x8*)p;
  };

  f32x4 acc[8][4];
#pragma unroll
  for (int m = 0; m < 8; ++m)
#pragma unroll
    for (int n = 0; n < 4; ++n) acc[m][n] = {0.f, 0.f, 0.f, 0.f};

  const int NT = K_TOT / 64;  // 32 K-tiles

  stageA(0, 0, 0); stageA(1, 0, 0);
  stageB(0, 0, 0); stageB(1, 0, 0);
  stageB(0, 1, 1); stageB(1, 1, 1);
  WAIT_VM0();
  BARRIER();

  bf16x8 bq[4][2];
  for (int t = 0; t < NT; ++t) {
    const int c = t & 1;
#pragma unroll
    for (int q = 0; q < 4; ++q) {
      bf16x8 a0 = ldA(c, 2 * q, 0);
      bf16x8 a0k = ldA(c, 2 * q, 1);
      bf16x8 a1 = ldA(c, 2 * q + 1, 0);
      bf16x8 a1k = ldA(c, 2 * q + 1, 1);
      if (q == 0) {
#pragma unroll
        for (int n = 0; n < 4; ++n) {
          bq[n][0] = ldB(c, n, 0);
          bq[n][1] = ldB(c, n, 1);
        }
      }
      if (q == 0 && t + 1 < NT) stageA(0, c ^ 1, t + 1);
      if (q == 1 && t + 1 < NT) stageA(1, c ^ 1, t + 1);
      if (q == 2 && t + 2 < NT) stageB(0, c, t + 2);
      if (q == 3) {
        if (t + 2 < NT) { stageB(1, c, t + 2); WAIT_VM4(); }
        else            { WAIT_VM0(); }
      }
      BARRIER();
      WAIT_LGKM0();
      __builtin_amdgcn_s_setprio(1);
#pragma unroll
      for (int n = 0; n < 4; ++n) {
        acc[2 * q][n]     = __builtin_amdgcn_mfma_f32_16x16x32_bf16(bq[n][0], a0,  acc[2 * q][n],     0, 0, 0);
        acc[2 * q][n]     = __builtin_amdgcn_mfma_f32_16x16x32_bf16(bq[n][1], a0k, acc[2 * q][n],     0, 0, 0);
        acc[2 * q + 1][n] = __builtin_amdgcn_mfma_f32_16x16x32_bf16(bq[n][0], a1,  acc[2 * q + 1][n], 0, 0, 0);
        acc[2 * q + 1][n] = __builtin_amdgcn_mfma_f32_16x16x32_bf16(bq[n][1], a1k, acc[2 * q + 1][n], 0, 0, 0);
      }
      __builtin_amdgcn_s_setprio(0);
      BARRIER();
    }
  }

  // epilogue (swapped-D layout): M-sub = fr, N-sub = g*4 + j.
  f32x4 biasv[4];
#pragma unroll
  for (int n = 0; n < 4; ++n)
    biasv[n] = *(const f32x4*)&bias[n0 + wn * 64 + n * 16 + g * 4];
#pragma unroll
  for (int m = 0; m < 8; ++m) {
    float* rowp = Y + (size_t)(m0 + wm * 128 + m * 16 + fr) * N_TOT;
#pragma unroll
    for (int n = 0; n < 4; ++n) {
      f32x4 v = acc[m][n] + biasv[n];
      *(f32x4*)&rowp[n0 + wn * 64 + n * 16 + g * 4] = v;
    }
  }
}

// ---------------------------------------------------------------------------
// Fallback GEMM (verified round 1): 128^2 tile, in-kernel fp32->bf16 A staging.
// ---------------------------------------------------------------------------
__global__ __launch_bounds__(256, 2) void gemm_fb_kernel(
    const float* __restrict__ X, const unsigned short* __restrict__ W,
    const float* __restrict__ bias, float* __restrict__ Y) {
  __shared__ __align__(16) unsigned short Alds[2][128 * 32];
  __shared__ __align__(16) unsigned short Blds[2][128 * 32];
  const int tid = threadIdx.x;
  const int lane = tid & 63;
  const int wid = tid >> 6;
  const int wm = wid >> 1, wn = wid & 1;
  int bid = blockIdx.x;
  int wgid = (bid & 7) * (2048 / 8) + (bid >> 3);
  const int m0 = (wgid >> 4) * 128, n0 = (wgid & 15) * 128;
  const int ar = tid >> 3, ac = (tid & 7) * 4;
  const int br = (tid >> 2), bc = (tid & 3) * 8;
  f32x4 acc[4][4];
#pragma unroll
  for (int m = 0; m < 4; ++m)
#pragma unroll
    for (int n = 0; n < 4; ++n) acc[m][n] = {0.f, 0.f, 0.f, 0.f};
  f32x4 apre[4];
  auto stA_l = [&](int k0) {
#pragma unroll
    for (int p = 0; p < 4; ++p)
      apre[p] = *(const f32x4*)&X[(size_t)(m0 + p * 32 + ar) * K_TOT + k0 + ac];
  };
  auto stA_w = [&](int buf) {
#pragma unroll
    for (int p = 0; p < 4; ++p) {
      us4 h;
      h[0] = f2bf(apre[p][0]); h[1] = f2bf(apre[p][1]);
      h[2] = f2bf(apre[p][2]); h[3] = f2bf(apre[p][3]);
      *(us4*)&Alds[buf][(p * 32 + ar) * 32 + ac] = h;
    }
  };
  auto stB = [&](int k0, int buf) {
#pragma unroll
    for (int i = 0; i < 2; ++i)
      gld_lds16(&W[(size_t)(n0 + i * 64 + br) * K_TOT + k0 + bc],
                &Blds[buf][i * 2048 + wid * 512]);
  };
  auto comp = [&](int buf) {
    const unsigned short* Ab = &Alds[buf][(wm * 64 + (lane & 15)) * 32 + (lane >> 4) * 8];
    const unsigned short* Bb = &Blds[buf][(wn * 64 + (lane & 15)) * 32 + (lane >> 4) * 8];
    bf16x8 af[4], bfv[4];
#pragma unroll
    for (int m = 0; m < 4; ++m) af[m] = *(const bf16x8*)(Ab + m * 16 * 32);
#pragma unroll
    for (int n = 0; n < 4; ++n) bfv[n] = *(const bf16x8*)(Bb + n * 16 * 32);
#pragma unroll
    for (int m = 0; m < 4; ++m)
#pragma unroll
      for (int n = 0; n < 4; ++n)
        acc[m][n] = __builtin_amdgcn_mfma_f32_16x16x32_bf16(af[m], bfv[n], acc[m][n], 0, 0, 0);
  };
  stA_l(0); stB(0, 0); stA_w(0);
  __syncthreads();
  for (int kt = 0; kt < 64; ++kt) {
    const int cur = kt & 1, nxt = cur ^ 1;
    if (kt + 1 < 64) { stA_l((kt + 1) * 32); stB((kt + 1) * 32, nxt); }
    comp(cur);
    if (kt + 1 < 64) stA_w(nxt);
    __syncthreads();
  }
  const int col = lane & 15, rb = (lane >> 4) * 4;
#pragma unroll
  for (int n = 0; n < 4; ++n) {
    const int gc = n0 + wn * 64 + n * 16 + col;
    const float bv = bias[gc];
#pragma unroll
    for (int m = 0; m < 4; ++m)
#pragma unroll
      for (int j = 0; j < 4; ++j)
        Y[(size_t)(m0 + wm * 64 + m * 16 + rb + j) * N_TOT + gc] = acc[m][n][j] + bv;
  }
}

extern "C" void kernel_launch(void* const* d_in, const int* in_sizes, int n_in,
                              void* d_out, int out_size, void* d_ws, size_t ws_size,
                              hipStream_t stream) {
  const float* x    = (const float*)d_in[0];
  const float* c1   = (const float*)d_in[1];
  const float* c2   = (const float*)d_in[2];
  const float* bias = (const float*)d_in[3];
  float* y          = (float*)d_out;
  unsigned short* W = (unsigned short*)d_ws;                        // 8 MB
  unsigned short* Xb = (unsigned short*)((char*)d_ws + (8u << 20)); // 64 MB

  const size_t need = (size_t)(8u << 20) + (size_t)M_TOT * K_TOT * 2;
  if (ws_size >= need) {
    prep_kernel<<<16384 + 16384, 256, 0, stream>>>(x, Xb, c1, c2, W, 16384);
    gemm8p_kernel<<<(M_TOT / 256) * (N_TOT / 256), 512, 0, stream>>>(Xb, W, bias, y);
  } else {
    prep_kernel<<<16384, 256, 0, stream>>>(x, nullptr, c1, c2, W, 0);  // W only
    gemm_fb_kernel<<<(M_TOT / 128) * (N_TOT / 128), 256, 0, stream>>>(x, W, bias, y);
  }
}

// Round 6
// 177.730 us; speedup vs baseline: 1.7607x; 1.0180x over previous
//
#include <hip/hip_runtime.h>
#include <stdint.h>

// y[b,s,m] = sum_n x[b,s,n] * W[m,n] + bias[m], W from TT cores (bf16, built once).
// Pipeline: prep (build_w + convert_x fused, one dispatch) -> 8-phase 256^2 GEMM.
// GEMM: A = bf16 X (pre-converted), B = bf16 W, both via global_load_lds.
// B fragments are REGISTER-PIPELINED: tile t's B frags live in regs (bqc);
// tile t+1's are prefetched from LDS spread over phases q1/q2 (4 reads each),
// flattening the per-phase LDS-read profile to 4/8/8/4 (was 12/4/4/4).
// MFMA operands swapped (W-frag first) -> D transposed -> f32x4 coalesced stores.

typedef __attribute__((ext_vector_type(8))) __bf16 bf16x8;
typedef __attribute__((ext_vector_type(4))) float f32x4;
typedef __attribute__((ext_vector_type(4))) unsigned short us4;
typedef __attribute__((ext_vector_type(8))) unsigned short us8;

#define M_TOT 16384
#define N_TOT 2048
#define K_TOT 2048

__device__ __forceinline__ unsigned short f2bf(float f) {
  union { float f; unsigned u; } v; v.f = f;
  unsigned u = v.u;
  u += 0x7FFFu + ((u >> 16) & 1u);   // RNE
  return (unsigned short)(u >> 16);
}

__device__ __forceinline__ void gld_lds16(const void* g, void* l) {
  __builtin_amdgcn_global_load_lds(
      (const __attribute__((address_space(1))) unsigned int*)g,
      (__attribute__((address_space(3))) unsigned int*)l, 16, 0, 0);
}

#define BARRIER() __builtin_amdgcn_s_barrier()
#define WAIT_LGKM0() asm volatile("s_waitcnt lgkmcnt(0)" ::: "memory")
#define WAIT_VM(N) asm volatile("s_waitcnt vmcnt(" #N ")" ::: "memory")

// ---------------------------------------------------------------------------
// Kernel 1: fused prep. Blocks [0,nconv): X fp32->bf16 (1 us8/thread);
// blocks [nconv, nconv+16384): build W bf16 from TT cores.
// ---------------------------------------------------------------------------
__global__ void prep_kernel(const float* __restrict__ X,
                            unsigned short* __restrict__ Xb,
                            const float* __restrict__ c1,
                            const float* __restrict__ c2,
                            unsigned short* __restrict__ W,
                            int nconv) {
  const int bid = blockIdx.x;
  if (bid < nconv) {
    const size_t i = (size_t)bid * 256 + threadIdx.x;   // us8 index
    f32x4 a = ((const f32x4*)X)[i * 2];
    f32x4 b = ((const f32x4*)X)[i * 2 + 1];
    us8 h;
    h[0] = f2bf(a[0]); h[1] = f2bf(a[1]); h[2] = f2bf(a[2]); h[3] = f2bf(a[3]);
    h[4] = f2bf(b[0]); h[5] = f2bf(b[1]); h[6] = f2bf(b[2]); h[7] = f2bf(b[3]);
    ((us8*)Xb)[i] = h;
  } else {
    int idx = (bid - nconv) * 256 + threadIdx.x;   // n*2048 + k
    int k = idx & (K_TOT - 1);
    int n = idx >> 11;
    int i = n >> 9, ob = n & 511;
    int m1 = ob >> 4, m2 = ob & 15;
    int j = k >> 9, ib = k & 511;
    int n1 = ib >> 4, n2 = ib & 15;
    const float* a = c1 + ((((i * 4 + j) * 32 + m1) * 32 + n1) * 16);
    const float* b = c2 + ((i * 4 + j) * 4096 + m2 * 16 + n2);
    float s = 0.f;
#pragma unroll
    for (int r = 0; r < 16; ++r) s += a[r] * b[r * 256];
    W[idx] = f2bf(s);
  }
}

// ---------------------------------------------------------------------------
// Kernel 2: 8-phase 256x256 bf16 GEMM, BK=64, 512 thr (8 waves 2Mx4N).
// LDS 128 KiB: [buf2][sect4][128x64 bf16]; sect 0/1 = A halves, 2/3 = B halves.
// XOR swizzle both-sides (inverse-swizzled global source + swizzled ds_read).
// vmcnt chain: q1 WAIT(4) drains B(t+1) [enables bqn LDS prefetch],
// q3 WAIT(4) drains A(t+1); B(t+2) stays in flight. Never 0 mid-loop.
// ---------------------------------------------------------------------------
__global__ __launch_bounds__(512, 2) void gemm8p_kernel(
    const unsigned short* __restrict__ Xb, const unsigned short* __restrict__ W,
    const float* __restrict__ bias, float* __restrict__ Y) {
  __shared__ __align__(16) unsigned short lds[2][4][128 * 64];

  const int tid = threadIdx.x;
  const int lane = tid & 63;
  const int wid = tid >> 6;
  const int wm = wid >> 2, wn = wid & 3;     // 2 x 4 wave grid

  const int bid = blockIdx.x;
  const int xcd = bid & 7, loc = bid >> 3;
  const int mblk = xcd * 8 + (loc >> 3);     // 0..63
  const int nblk = loc & 7;                  // 0..7
  const int m0 = mblk * 256, n0 = nblk * 256;

  const int fr = lane & 15, g = lane >> 4;
  const int swz = fr & 7;
  const int blkB0 = ((0 + g) ^ swz) * 16;    // ksub=0 byte offset of 16B block
  const int blkB1 = ((4 + g) ^ swz) * 16;    // ksub=1
  const int arow = fr * 128;
  const int brow = ((wn & 1) * 64 + fr) * 128;

  const int sr = tid >> 3;
  const int sc = ((tid & 7) ^ (sr & 7)) * 8;

  auto stageA = [&](int half, int buf, int kt) {
    const unsigned short* base = Xb + (size_t)(m0 + half * 128) * K_TOT + kt * 64 + sc;
#pragma unroll
    for (int i = 0; i < 2; ++i)
      gld_lds16(base + (size_t)(i * 64 + sr) * K_TOT,
                &lds[buf][half][i * 4096 + wid * 512]);
  };
  auto stageB = [&](int half, int buf, int kt) {
    const unsigned short* base = W + (size_t)(n0 + half * 128) * K_TOT + kt * 64 + sc;
#pragma unroll
    for (int i = 0; i < 2; ++i)
      gld_lds16(base + (size_t)(i * 64 + sr) * K_TOT,
                &lds[buf][2 + half][i * 4096 + wid * 512]);
  };
  auto ldA = [&](int c, int m, int ks) -> bf16x8 {
    const char* p = (const char*)&lds[c][wm][0] + arow + m * 2048 + (ks ? blkB1 : blkB0);
    return *(const bf16x8*)p;
  };
  auto ldB = [&](int c, int n, int ks) -> bf16x8 {
    const char* p = (const char*)&lds[c][2 + (wn >> 1)][0] + brow + n * 2048 + (ks ? blkB1 : blkB0);
    return *(const bf16x8*)p;
  };

  f32x4 acc[8][4];
#pragma unroll
  for (int m = 0; m < 8; ++m)
#pragma unroll
    for (int n = 0; n < 4; ++n) acc[m][n] = {0.f, 0.f, 0.f, 0.f};

  const int NT = K_TOT / 64;  // 32 K-tiles (even)

  // prologue: tile0 (A+B) -> buf0, B of tile1 -> buf1
  stageA(0, 0, 0); stageA(1, 0, 0);       // 4 loads
  stageB(0, 0, 0); stageB(1, 0, 0);       // 4
  stageB(0, 1, 1); stageB(1, 1, 1);       // 4 (tile1 B)
  WAIT_VM(4);                             // tile0 landed; B(1) in flight
  BARRIER();

  bf16x8 bqX[4][2], bqY[4][2];
  // load tile0's B frags into regs (covered by first in-loop lgkmcnt(0))
#pragma unroll
  for (int n = 0; n < 4; ++n) {
    bqX[n][0] = ldB(0, n, 0);
    bqX[n][1] = ldB(0, n, 1);
  }

  auto body = [&](int t, int c, bf16x8 (&bqc)[4][2], bf16x8 (&bqn)[4][2]) {
#pragma unroll
    for (int q = 0; q < 4; ++q) {
      bf16x8 a0  = ldA(c, 2 * q, 0);
      bf16x8 a0k = ldA(c, 2 * q, 1);
      bf16x8 a1  = ldA(c, 2 * q + 1, 0);
      bf16x8 a1k = ldA(c, 2 * q + 1, 1);
      if (q == 0 && t + 1 < NT) stageA(0, c ^ 1, t + 1);
      if (q == 1) {
        if (t + 1 < NT) {
          stageA(1, c ^ 1, t + 1);
          WAIT_VM(4);                      // B(t+1) landed (A(t+1) in flight)
          bqn[0][0] = ldB(c ^ 1, 0, 0); bqn[0][1] = ldB(c ^ 1, 0, 1);
          bqn[1][0] = ldB(c ^ 1, 1, 0); bqn[1][1] = ldB(c ^ 1, 1, 1);
        }
      }
      if (q == 2) {
        if (t + 2 < NT) stageB(0, c, t + 2);
        if (t + 1 < NT) {
          bqn[2][0] = ldB(c ^ 1, 2, 0); bqn[2][1] = ldB(c ^ 1, 2, 1);
          bqn[3][0] = ldB(c ^ 1, 3, 0); bqn[3][1] = ldB(c ^ 1, 3, 1);
        }
      }
      if (q == 3) {
        if (t + 2 < NT) { stageB(1, c, t + 2); WAIT_VM(4); }  // A(t+1) landed
        else            { WAIT_VM(0); }                        // tail drain
      }
      BARRIER();
      WAIT_LGKM0();
      __builtin_amdgcn_s_setprio(1);
#pragma unroll
      for (int n = 0; n < 4; ++n) {
        acc[2 * q][n]     = __builtin_amdgcn_mfma_f32_16x16x32_bf16(bqc[n][0], a0,  acc[2 * q][n],     0, 0, 0);
        acc[2 * q][n]     = __builtin_amdgcn_mfma_f32_16x16x32_bf16(bqc[n][1], a0k, acc[2 * q][n],     0, 0, 0);
        acc[2 * q + 1][n] = __builtin_amdgcn_mfma_f32_16x16x32_bf16(bqc[n][0], a1,  acc[2 * q + 1][n], 0, 0, 0);
        acc[2 * q + 1][n] = __builtin_amdgcn_mfma_f32_16x16x32_bf16(bqc[n][1], a1k, acc[2 * q + 1][n], 0, 0, 0);
      }
      __builtin_amdgcn_s_setprio(0);
      BARRIER();
    }
  };

  for (int tt = 0; tt < NT; tt += 2) {
    body(tt,     0, bqX, bqY);   // uses bqX, prefetches tile tt+1 B -> bqY
    body(tt + 1, 1, bqY, bqX);   // uses bqY, prefetches tile tt+2 B -> bqX
  }

  // epilogue (swapped-D layout): M-sub = fr, N-sub = g*4 + j.
  f32x4 biasv[4];
#pragma unroll
  for (int n = 0; n < 4; ++n)
    biasv[n] = *(const f32x4*)&bias[n0 + wn * 64 + n * 16 + g * 4];
#pragma unroll
  for (int m = 0; m < 8; ++m) {
    float* rowp = Y + (size_t)(m0 + wm * 128 + m * 16 + fr) * N_TOT;
#pragma unroll
    for (int n = 0; n < 4; ++n) {
      f32x4 v = acc[m][n] + biasv[n];
      *(f32x4*)&rowp[n0 + wn * 64 + n * 16 + g * 4] = v;
    }
  }
}

// ---------------------------------------------------------------------------
// Fallback GEMM (verified round 1): 128^2 tile, in-kernel fp32->bf16 A staging.
// ---------------------------------------------------------------------------
__global__ __launch_bounds__(256, 2) void gemm_fb_kernel(
    const float* __restrict__ X, const unsigned short* __restrict__ W,
    const float* __restrict__ bias, float* __restrict__ Y) {
  __shared__ __align__(16) unsigned short Alds[2][128 * 32];
  __shared__ __align__(16) unsigned short Blds[2][128 * 32];
  const int tid = threadIdx.x;
  const int lane = tid & 63;
  const int wid = tid >> 6;
  const int wm = wid >> 1, wn = wid & 1;
  int bid = blockIdx.x;
  int wgid = (bid & 7) * (2048 / 8) + (bid >> 3);
  const int m0 = (wgid >> 4) * 128, n0 = (wgid & 15) * 128;
  const int ar = tid >> 3, ac = (tid & 7) * 4;
  const int br = (tid >> 2), bc = (tid & 3) * 8;
  f32x4 acc[4][4];
#pragma unroll
  for (int m = 0; m < 4; ++m)
#pragma unroll
    for (int n = 0; n < 4; ++n) acc[m][n] = {0.f, 0.f, 0.f, 0.f};
  f32x4 apre[4];
  auto stA_l = [&](int k0) {
#pragma unroll
    for (int p = 0; p < 4; ++p)
      apre[p] = *(const f32x4*)&X[(size_t)(m0 + p * 32 + ar) * K_TOT + k0 + ac];
  };
  auto stA_w = [&](int buf) {
#pragma unroll
    for (int p = 0; p < 4; ++p) {
      us4 h;
      h[0] = f2bf(apre[p][0]); h[1] = f2bf(apre[p][1]);
      h[2] = f2bf(apre[p][2]); h[3] = f2bf(apre[p][3]);
      *(us4*)&Alds[buf][(p * 32 + ar) * 32 + ac] = h;
    }
  };
  auto stB = [&](int k0, int buf) {
#pragma unroll
    for (int i = 0; i < 2; ++i)
      gld_lds16(&W[(size_t)(n0 + i * 64 + br) * K_TOT + k0 + bc],
                &Blds[buf][i * 2048 + wid * 512]);
  };
  auto comp = [&](int buf) {
    const unsigned short* Ab = &Alds[buf][(wm * 64 + (lane & 15)) * 32 + (lane >> 4) * 8];
    const unsigned short* Bb = &Blds[buf][(wn * 64 + (lane & 15)) * 32 + (lane >> 4) * 8];
    bf16x8 af[4], bfv[4];
#pragma unroll
    for (int m = 0; m < 4; ++m) af[m] = *(const bf16x8*)(Ab + m * 16 * 32);
#pragma unroll
    for (int n = 0; n < 4; ++n) bfv[n] = *(const bf16x8*)(Bb + n * 16 * 32);
#pragma unroll
    for (int m = 0; m < 4; ++m)
#pragma unroll
      for (int n = 0; n < 4; ++n)
        acc[m][n] = __builtin_amdgcn_mfma_f32_16x16x32_bf16(af[m], bfv[n], acc[m][n], 0, 0, 0);
  };
  stA_l(0); stB(0, 0); stA_w(0);
  __syncthreads();
  for (int kt = 0; kt < 64; ++kt) {
    const int cur = kt & 1, nxt = cur ^ 1;
    if (kt + 1 < 64) { stA_l((kt + 1) * 32); stB((kt + 1) * 32, nxt); }
    comp(cur);
    if (kt + 1 < 64) stA_w(nxt);
    __syncthreads();
  }
  const int col = lane & 15, rb = (lane >> 4) * 4;
#pragma unroll
  for (int n = 0; n < 4; ++n) {
    const int gc = n0 + wn * 64 + n * 16 + col;
    const float bv = bias[gc];
#pragma unroll
    for (int m = 0; m < 4; ++m)
#pragma unroll
      for (int j = 0; j < 4; ++j)
        Y[(size_t)(m0 + wm * 64 + m * 16 + rb + j) * N_TOT + gc] = acc[m][n][j] + bv;
  }
}

extern "C" void kernel_launch(void* const* d_in, const int* in_sizes, int n_in,
                              void* d_out, int out_size, void* d_ws, size_t ws_size,
                              hipStream_t stream) {
  const float* x    = (const float*)d_in[0];
  const float* c1   = (const float*)d_in[1];
  const float* c2   = (const float*)d_in[2];
  const float* bias = (const float*)d_in[3];
  float* y          = (float*)d_out;
  unsigned short* W = (unsigned short*)d_ws;                        // 8 MB
  unsigned short* Xb = (unsigned short*)((char*)d_ws + (8u << 20)); // 64 MB

  const size_t need = (size_t)(8u << 20) + (size_t)M_TOT * K_TOT * 2;
  if (ws_size >= need) {
    prep_kernel<<<16384 + 16384, 256, 0, stream>>>(x, Xb, c1, c2, W, 16384);
    gemm8p_kernel<<<(M_TOT / 256) * (N_TOT / 256), 512, 0, stream>>>(Xb, W, bias, y);
  } else {
    prep_kernel<<<16384, 256, 0, stream>>>(x, nullptr, c1, c2, W, 0);  // W only
    gemm_fb_kernel<<<(M_TOT / 128) * (N_TOT / 128), 256, 0, stream>>>(x, W, bias, y);
  }
}